// Round 1
// 121.688 us; speedup vs baseline: 1.0026x; 1.0026x over previous
//
#include <hip/hip_runtime.h>
#include <hip/hip_bf16.h>

// EasyExprGNN: B=8, S=4096, N=32, H=32, D=64, O=32. T = B*S = 32768 tokens.
//
// Folded formulation (exact algebra):
//   per (token, n): var = quadratic(nb, ei) via 6 scalars; inv = rsqrt(var+eps)
//                   r_j = relu((nb*Ag_j + ei*Cg_j + Dg_j)*inv + nlb_j);  nsum_j = sum_n r_j
//   self: e_j = relu((ex*Asg_j + Dsg_j)*inv_s + slb_j)
//   y_m = sum_k e_k*G[k][m] + sum_k nsum_k*G[32+k][m] + cvec[m]   (G = branchW2 (x) hW1 fused)
//   out_j = relu(LN64(y)*hlg+hlb) @ hW2 + hb2; masked -> 0

#define LN_EPS 1e-5f

// ---------------- fold kernel: precompute folded weights into ws ----------------
// ws float layout (all blocks 16B aligned):
//   [0,32) Ag  [32,64) Cg  [64,96) Dg  [96,128) nlb
//   [128,134) qaa, qcc, qdd/32+eps, 2*qac, 2*qad, 2*qcd   (all /32)
//   [136,168) Asg [168,200) Dsg [200,232) slb
//   [232,235) saa/32, 2*sad/32, sdd/32+eps
//   [256,4352) G[64][64] (k-major; k<32 = self channels via sW2, k>=32 = nsum via nW2)
//   [4352,4416) cvec[64]
__global__ __launch_bounds__(256) void gnn_fold(
    const float* __restrict__ nW1, const float* __restrict__ nb1,
    const float* __restrict__ nlg, const float* __restrict__ nlb,
    const float* __restrict__ nW2, const float* __restrict__ nb2,
    const float* __restrict__ sW1, const float* __restrict__ sb1,
    const float* __restrict__ slg, const float* __restrict__ slb,
    const float* __restrict__ sW2, const float* __restrict__ sb2,
    const float* __restrict__ hW1, const float* __restrict__ hb1,
    float* __restrict__ ws)
{
    int tid = blockIdx.x * 256 + threadIdx.x;   // 0..4095 -> one G entry each
    int k = tid >> 6, m = tid & 63;
    float acc = 0.f;
    if (k < 32) {
        #pragma unroll 8
        for (int i = 0; i < 32; ++i) acc = fmaf(sW2[k*32 + i], hW1[i*64 + m], acc);
    } else {
        int kk = k - 32;
        #pragma unroll 8
        for (int i = 0; i < 32; ++i) acc = fmaf(nW2[kk*32 + i], hW1[(32 + i)*64 + m], acc);
    }
    ws[256 + k*64 + m] = acc;

    if (blockIdx.x == 0) {
        int t = threadIdx.x;
        if (t < 64) {
            // cvec[m] = hb1[m] + sb2 @ hW1_top[:,m] + 32 * nb2 @ hW1_bot[:,m]
            float c = hb1[t];
            for (int i = 0; i < 32; ++i) {
                c = fmaf(sb2[i], hW1[i*64 + t], c);
                c = fmaf(32.f * nb2[i], hW1[(32 + i)*64 + t], c);
            }
            ws[4352 + t] = c;
        } else if (t < 96) {
            int j = t - 64;
            float m0 = 0.f, m1 = 0.f, mb = 0.f;
            for (int i = 0; i < 32; ++i) { m0 += nW1[i]; m1 += nW1[32 + i]; mb += nb1[i]; }
            m0 *= (1.f/32.f); m1 *= (1.f/32.f); mb *= (1.f/32.f);
            float a = nW1[j] - m0, c = nW1[32 + j] - m1, d = nb1[j] - mb;
            ws[j]       = a * nlg[j];
            ws[32 + j]  = c * nlg[j];
            ws[64 + j]  = d * nlg[j];
            ws[96 + j]  = nlb[j];
            float ms = 0.f, msb = 0.f;
            for (int i = 0; i < 32; ++i) { ms += sW1[i]; msb += sb1[i]; }
            ms *= (1.f/32.f); msb *= (1.f/32.f);
            float as = sW1[j] - ms, ds = sb1[j] - msb;
            ws[136 + j] = as * slg[j];
            ws[168 + j] = ds * slg[j];
            ws[200 + j] = slb[j];
        } else if (t == 96) {
            float m0 = 0.f, m1 = 0.f, mb = 0.f;
            for (int i = 0; i < 32; ++i) { m0 += nW1[i]; m1 += nW1[32 + i]; mb += nb1[i]; }
            m0 *= (1.f/32.f); m1 *= (1.f/32.f); mb *= (1.f/32.f);
            float qaa=0,qcc=0,qdd=0,qac=0,qad=0,qcd=0;
            for (int j = 0; j < 32; ++j) {
                float a = nW1[j] - m0, c = nW1[32 + j] - m1, d = nb1[j] - mb;
                qaa += a*a; qcc += c*c; qdd += d*d; qac += a*c; qad += a*d; qcd += c*d;
            }
            ws[128] = qaa*(1.f/32.f);
            ws[129] = qcc*(1.f/32.f);
            ws[130] = qdd*(1.f/32.f) + LN_EPS;     // eps folded in
            ws[131] = 2.f*qac*(1.f/32.f);          // cross terms pre-doubled
            ws[132] = 2.f*qad*(1.f/32.f);
            ws[133] = 2.f*qcd*(1.f/32.f);
            float ms = 0.f, msb = 0.f;
            for (int i = 0; i < 32; ++i) { ms += sW1[i]; msb += sb1[i]; }
            ms *= (1.f/32.f); msb *= (1.f/32.f);
            float saa=0, sad=0, sdd=0;
            for (int j = 0; j < 32; ++j) {
                float as = sW1[j] - ms, ds = sb1[j] - msb;
                saa += as*as; sad += as*ds; sdd += ds*ds;
            }
            ws[232] = saa*(1.f/32.f);
            ws[233] = 2.f*sad*(1.f/32.f);
            ws[234] = sdd*(1.f/32.f) + LN_EPS;
        }
    }
}

// ---------------- main kernel: 64 tokens per block of 512 threads (8 thr/token) ----------------
// Occupancy: 512 blocks x 8 waves = 4096 waves -> 4 waves/SIMD (2x the old 256-thr version).
// LDS 38144 B -> up to 4 resident blocks/CU (launch_bounds caps VGPR at 128).
__global__ __launch_bounds__(512, 4) void gnn_main(
    const float* __restrict__ expr, const float* __restrict__ neighbors,
    const float* __restrict__ edge_info, const int* __restrict__ mask,
    const float* __restrict__ hlg, const float* __restrict__ hlb,
    const float* __restrict__ hW2, const float* __restrict__ hb2,
    const float* __restrict__ ws, float* __restrict__ out)
{
    __shared__ float s_feat[64 * 33 * 2];   // (tok*33+n)*2 + {0:nb, 1:ei}; odd stride -> no conflicts
    __shared__ float s_X[64 * 65];          // tok*65 + k  (phase B input X, reused for Y')
    __shared__ float s_red[64 * 17];        // tok*17 + w*2 + {0,1}  LN partials (8 waves)
    __shared__ float s_expr[64];

    const int t  = threadIdx.x;
    const int g0 = blockIdx.x * 64;         // first global token of this block
    const int bb = g0 >> 12;                // batch (S=4096 divides 64 evenly -> no crossing)
    const int s0 = g0 & 4095;
    const float* nbp = neighbors + ((size_t)bb * 32 * 4096 + s0);
    const float* eip = edge_info + (size_t)g0 * 32;

    // ---- stage neighbors (transposing) + edge_info, one dwordx4 load each ----
    {
        int n = t >> 4, c4 = t & 15;        // 16-lane groups read 256B contiguous per n-row
        float4 v = *(const float4*)&nbp[n * 4096 + c4 * 4];
        int base = ((c4 * 4) * 33 + n) * 2;
        s_feat[base      ] = v.x;           // col stride = 66 words
        s_feat[base +  66] = v.y;
        s_feat[base + 132] = v.z;
        s_feat[base + 198] = v.w;
    }
    {
        int tk = t >> 3, n4 = t & 7;
        float4 v = *(const float4*)&eip[tk * 32 + n4 * 4];
        int base = (tk * 33 + n4 * 4) * 2 + 1;
        s_feat[base    ] = v.x;
        s_feat[base + 2] = v.y;
        s_feat[base + 4] = v.z;
        s_feat[base + 6] = v.w;
    }
    if (t < 64) s_expr[t] = expr[g0 + t];
    __syncthreads();

    // ---- phase A: neighbor accumulation. 8 threads/token, 4 channels each.
    //      inv computed inline (6 fma + rsqrt) -> no s_inv pass, no extra barrier.
    const int tok = t >> 3;
    const int jb  = (t & 7) * 4;
    float Ag[4], Cg[4], Dg[4], lbv[4];
    *(float4*)Ag  = *(const float4*)&ws[jb];
    *(float4*)Cg  = *(const float4*)&ws[32 + jb];
    *(float4*)Dg  = *(const float4*)&ws[64 + jb];
    *(float4*)lbv = *(const float4*)&ws[96 + jb];
    const float qaa  = ws[128], qcc  = ws[129], qddp = ws[130];
    const float qac2 = ws[131], qad2 = ws[132], qcd2 = ws[133];

    float nsum[4] = {0.f, 0.f, 0.f, 0.f};
    #pragma unroll 8
    for (int n = 0; n < 32; ++n) {
        float2 f = *(const float2*)&s_feat[(tok * 33 + n) * 2];   // 8-lane broadcast, conflict-free
        float v = fmaf(f.x, fmaf(qaa, f.x, qad2),
                  fmaf(f.y, fmaf(qcc, f.y, qcd2),
                  fmaf(qac2, f.x * f.y, qddp)));
        float inv = rsqrtf(v);
        #pragma unroll
        for (int i = 0; i < 4; ++i) {
            float r = fmaf(f.x, Ag[i], Dg[i]);
            r = fmaf(f.y, Cg[i], r);
            r = fmaf(r, inv, lbv[i]);
            nsum[i] += fmaxf(r, 0.f);
        }
    }

    // ---- self branch + write X = [e | nsum] ----
    {
        float ex = s_expr[tok];
        float As[4], Ds[4], sl[4];
        *(float4*)As = *(const float4*)&ws[136 + jb];
        *(float4*)Ds = *(const float4*)&ws[168 + jb];
        *(float4*)sl = *(const float4*)&ws[200 + jb];
        float vs   = fmaf(ex, fmaf(ws[232], ex, ws[233]), ws[234]);
        float invs = rsqrtf(vs);
        #pragma unroll
        for (int i = 0; i < 4; ++i) {
            float r = fmaf(ex, As[i], Ds[i]);
            r = fmaf(r, invs, sl[i]);
            s_X[tok * 65 + jb + i]      = fmaxf(r, 0.f);
            s_X[tok * 65 + 32 + jb + i] = nsum[i];
        }
    }
    __syncthreads();

    // ---- phase B: y = X @ G + cvec. wave w owns channels [8w, 8w+8), lane = token ----
    const int w = __builtin_amdgcn_readfirstlane(t >> 6);  // wave-uniform -> s_load weights
    const int l = t & 63;
    const float* Gp = ws + 256 + w * 8;
    const float* cv = ws + 4352 + w * 8;
    float y[8];
    #pragma unroll
    for (int i = 0; i < 8; ++i) y[i] = cv[i];
    #pragma unroll 4
    for (int k = 0; k < 64; ++k) {
        float xk = s_X[l * 65 + k];                        // bank (l+k)%32: 2-way, free
        const float* gk = Gp + k * 64;
        #pragma unroll
        for (int i = 0; i < 8; ++i) y[i] = fmaf(xk, gk[i], y[i]);
    }

    // ---- LN over 64 channels (split across 8 waves) ----
    float sm = 0.f, s2 = 0.f;
    #pragma unroll
    for (int i = 0; i < 8; ++i) { sm += y[i]; s2 = fmaf(y[i], y[i], s2); }
    s_red[l * 17 + w * 2 + 0] = sm;
    s_red[l * 17 + w * 2 + 1] = s2;
    __syncthreads();          // also guarantees all phase-B reads of s_X are done
    float tot = 0.f, tot2 = 0.f;
    #pragma unroll
    for (int r = 0; r < 8; ++r) {
        tot  += s_red[l * 17 + r * 2 + 0];
        tot2 += s_red[l * 17 + r * 2 + 1];
    }
    float mean = tot * (1.f / 64.f);
    float var  = tot2 * (1.f / 64.f) - mean * mean;
    float linv = rsqrtf(var + LN_EPS);
    #pragma unroll
    for (int i = 0; i < 8; ++i) {
        float v = (y[i] - mean) * linv;
        v = fmaf(v, hlg[w * 8 + i], hlb[w * 8 + i]);
        s_X[l * 65 + w * 8 + i] = fmaxf(v, 0.f);           // reuse s_X for Y'
    }
    __syncthreads();

    // ---- phase C: out = Y' @ hW2 + hb2. wave w owns out channels [4w, 4w+4) ----
    const int ob = w * 4;
    int mk = mask[g0 + l];                                 // early load, hides latency
    float o[4];
    #pragma unroll
    for (int i = 0; i < 4; ++i) o[i] = hb2[ob + i];
    #pragma unroll 4
    for (int m = 0; m < 64; ++m) {
        float ym = s_X[l * 65 + m];
        const float* h2 = hW2 + m * 32 + ob;               // uniform -> s_load_dwordx4
        #pragma unroll
        for (int i = 0; i < 4; ++i) o[i] = fmaf(ym, h2[i], o[i]);
    }
    float4 ov = make_float4(o[0], o[1], o[2], o[3]);
    if (mk) ov = make_float4(0.f, 0.f, 0.f, 0.f);
    *(float4*)(out + (size_t)(g0 + l) * 32 + ob) = ov;
}

extern "C" void kernel_launch(void* const* d_in, const int* in_sizes, int n_in,
                              void* d_out, int out_size, void* d_ws, size_t ws_size,
                              hipStream_t stream) {
    const float* expr      = (const float*)d_in[0];
    const float* neighbors = (const float*)d_in[1];
    const float* edge_info = (const float*)d_in[2];
    const int*   mask      = (const int*)d_in[3];
    const float* nW1 = (const float*)d_in[4];
    const float* nb1 = (const float*)d_in[5];
    const float* nlg = (const float*)d_in[6];
    const float* nlb = (const float*)d_in[7];
    const float* nW2 = (const float*)d_in[8];
    const float* nb2 = (const float*)d_in[9];
    const float* sW1 = (const float*)d_in[10];
    const float* sb1 = (const float*)d_in[11];
    const float* slg = (const float*)d_in[12];
    const float* slb = (const float*)d_in[13];
    const float* sW2 = (const float*)d_in[14];
    const float* sb2 = (const float*)d_in[15];
    const float* hW1 = (const float*)d_in[16];
    const float* hb1 = (const float*)d_in[17];
    const float* hlg = (const float*)d_in[18];
    const float* hlb = (const float*)d_in[19];
    const float* hW2 = (const float*)d_in[20];
    const float* hb2 = (const float*)d_in[21];
    float* ws  = (float*)d_ws;
    float* out = (float*)d_out;

    gnn_fold<<<16, 256, 0, stream>>>(nW1, nb1, nlg, nlb, nW2, nb2,
                                     sW1, sb1, slg, slb, sW2, sb2,
                                     hW1, hb1, ws);
    gnn_main<<<512, 512, 0, stream>>>(expr, neighbors, edge_info, mask,
                                      hlg, hlb, hW2, hb2, ws, out);
}

// Round 2
// 121.128 us; speedup vs baseline: 1.0072x; 1.0046x over previous
//
#include <hip/hip_runtime.h>
#include <hip/hip_bf16.h>

// EasyExprGNN: B=8, S=4096, N=32, H=32, D=64, O=32. T = B*S = 32768 tokens.
//
// SINGLE-KERNEL formulation (no fold dispatch, no workspace):
//   smalls (per block, waves 0/1, shfl-reduced, hidden under staging):
//     Ag/Cg/Dg/lnb: mean-centered nW1 rows scaled by nlg; q* = LN variance quadratic
//     Asg/Dsg/slb + s* for the self branch
//   per (token,n): var = quad(nb,ei); inv = rsqrt(var) [eps folded]
//     r_j = relu((nb*Ag_j + ei*Cg_j + Dg_j)*inv + lnb_j); nsum_j = sum_n r_j
//   self: e_j = relu((ex*Asg_j + Dsg_j)*inv_s + slb_j)
//   X = [e | nsum]  (64 per token)
//   u[i]    = sum_k e_k    * sW2[k][i] + sb2[i]          (i in [0,32))
//   u[32+i] = sum_k nsum_k * nW2[k][i] + 32*nb2[i]
//   y[m]    = sum_k u[k] * hW1[k][m] + hb1[m]            (unfolded == folded algebra)
//   out = relu(LN64(y)*hlg+hlb) @ hW2 + hb2; masked -> 0

#define LN_EPS 1e-5f

__device__ __forceinline__ float wsum64(float v) {   // sum across all 64 lanes
    #pragma unroll
    for (int m = 1; m < 64; m <<= 1) v += __shfl_xor(v, m);
    return v;
}

// ---------------- 64 tokens per block of 512 threads (8 thr/token) ----------------
__global__ __launch_bounds__(512, 4) void gnn_all(
    const float* __restrict__ expr, const float* __restrict__ neighbors,
    const float* __restrict__ edge_info, const int* __restrict__ mask,
    const float* __restrict__ nW1, const float* __restrict__ nb1,
    const float* __restrict__ nlg, const float* __restrict__ nlb,
    const float* __restrict__ nW2, const float* __restrict__ nb2,
    const float* __restrict__ sW1, const float* __restrict__ sb1,
    const float* __restrict__ slg, const float* __restrict__ slb,
    const float* __restrict__ sW2, const float* __restrict__ sb2,
    const float* __restrict__ hW1, const float* __restrict__ hb1,
    const float* __restrict__ hlg, const float* __restrict__ hlb,
    const float* __restrict__ hW2, const float* __restrict__ hb2,
    float* __restrict__ out)
{
    __shared__ __align__(16) float s_feat[64 * 33 * 2];  // staging; reused as s_U later
    __shared__ __align__(16) float s_X[64 * 65];         // X = [e|nsum]; reused for Y'
    __shared__ __align__(16) float s_red[64 * 17];       // LN partials (8 waves)
    __shared__ __align__(16) float s_sm[240];            // folded small arrays
    __shared__ float s_expr[64];
    float* s_U = s_feat;                                 // u lives where s_feat was

    const int t  = threadIdx.x;
    const int g0 = blockIdx.x * 64;         // first global token of this block
    const int bb = g0 >> 12;                // batch (S=4096; 64 | 4096 -> no crossing)
    const int s0 = g0 & 4095;
    const float* nbp = neighbors + ((size_t)bb * 32 * 4096 + s0);
    const float* eip = edge_info + (size_t)g0 * 32;

    // ---- stage neighbors (transposing) + edge_info, one dwordx4 load each ----
    {
        int n = t >> 4, c4 = t & 15;        // 16-lane groups read 256B contiguous per n-row
        float4 v = *(const float4*)&nbp[n * 4096 + c4 * 4];
        int base = ((c4 * 4) * 33 + n) * 2;
        s_feat[base      ] = v.x;           // col stride = 66 words
        s_feat[base +  66] = v.y;
        s_feat[base + 132] = v.z;
        s_feat[base + 198] = v.w;
    }
    {
        int tk = t >> 3, n4 = t & 7;
        float4 v = *(const float4*)&eip[tk * 32 + n4 * 4];
        int base = (tk * 33 + n4 * 4) * 2 + 1;
        s_feat[base    ] = v.x;
        s_feat[base + 2] = v.y;
        s_feat[base + 4] = v.z;
        s_feat[base + 6] = v.w;
    }

    // ---- per-block fold of the small arrays (waves 0/1; hidden under staging) ----
    if (t < 64) {
        s_expr[t] = expr[g0 + t];
        int j = t & 31;
        bool lo = t < 32;
        float w0 = lo ? nW1[j]      : 0.f;
        float w1 = lo ? nW1[32 + j] : 0.f;
        float b1 = lo ? nb1[j]      : 0.f;
        float m0 = wsum64(w0) * (1.f/32.f);
        float m1 = wsum64(w1) * (1.f/32.f);
        float mb = wsum64(b1) * (1.f/32.f);
        float a = w0 - m0, c = w1 - m1, d = b1 - mb;
        float az = lo ? a : 0.f, cz = lo ? c : 0.f, dz = lo ? d : 0.f;
        float qaa = wsum64(az * az) * (1.f/32.f);
        float qcc = wsum64(cz * cz) * (1.f/32.f);
        float qdd = wsum64(dz * dz) * (1.f/32.f);
        float qac = wsum64(az * cz) * (2.f/32.f);
        float qad = wsum64(az * dz) * (2.f/32.f);
        float qcd = wsum64(cz * dz) * (2.f/32.f);
        if (lo) {
            float g = nlg[j];
            s_sm[j]      = a * g;
            s_sm[32 + j] = c * g;
            s_sm[64 + j] = d * g;
            s_sm[96 + j] = nlb[j];
        }
        if (t == 0) {
            s_sm[224] = qaa; s_sm[225] = qcc; s_sm[226] = qdd + LN_EPS;
            s_sm[227] = qac; s_sm[228] = qad; s_sm[229] = qcd;
        }
    } else if (t < 128) {
        int j = (t - 64) & 31;
        bool lo = t < 96;
        float w0 = lo ? sW1[j] : 0.f;
        float b0 = lo ? sb1[j] : 0.f;
        float ms  = wsum64(w0) * (1.f/32.f);
        float msb = wsum64(b0) * (1.f/32.f);
        float a = w0 - ms, d = b0 - msb;
        float az = lo ? a : 0.f, dz = lo ? d : 0.f;
        float saa = wsum64(az * az) * (1.f/32.f);
        float sad = wsum64(az * dz) * (2.f/32.f);
        float sdd = wsum64(dz * dz) * (1.f/32.f);
        if (lo) {
            float g = slg[j];
            s_sm[128 + j] = a * g;
            s_sm[160 + j] = d * g;
            s_sm[192 + j] = slb[j];
        }
        if (t == 96) { s_sm[230] = saa; s_sm[231] = sad; s_sm[232] = sdd + LN_EPS; }
    }
    __syncthreads();

    // ---- phase A: neighbor accumulation. 8 threads/token, 4 channels each ----
    const int tok = t >> 3;
    const int jb  = (t & 7) * 4;
    float Ag[4], Cg[4], Dg[4], lbv[4];
    *(float4*)Ag  = *(const float4*)&s_sm[jb];
    *(float4*)Cg  = *(const float4*)&s_sm[32 + jb];
    *(float4*)Dg  = *(const float4*)&s_sm[64 + jb];
    *(float4*)lbv = *(const float4*)&s_sm[96 + jb];
    const float qaa  = s_sm[224], qcc  = s_sm[225], qddp = s_sm[226];
    const float qac2 = s_sm[227], qad2 = s_sm[228], qcd2 = s_sm[229];

    float nsum[4] = {0.f, 0.f, 0.f, 0.f};
    #pragma unroll 8
    for (int n = 0; n < 32; ++n) {
        float2 f = *(const float2*)&s_feat[(tok * 33 + n) * 2];   // 8-lane broadcast
        float v = fmaf(f.x, fmaf(qaa, f.x, qad2),
                  fmaf(f.y, fmaf(qcc, f.y, qcd2),
                  fmaf(qac2, f.x * f.y, qddp)));
        float inv = rsqrtf(v);
        #pragma unroll
        for (int i = 0; i < 4; ++i) {
            float r = fmaf(f.x, Ag[i], Dg[i]);
            r = fmaf(f.y, Cg[i], r);
            r = fmaf(r, inv, lbv[i]);
            nsum[i] += fmaxf(r, 0.f);
        }
    }

    // ---- self branch + write X = [e | nsum] ----
    {
        float ex = s_expr[tok];
        float As[4], Ds[4], sl[4];
        *(float4*)As = *(const float4*)&s_sm[128 + jb];
        *(float4*)Ds = *(const float4*)&s_sm[160 + jb];
        *(float4*)sl = *(const float4*)&s_sm[192 + jb];
        float vs   = fmaf(ex, fmaf(s_sm[230], ex, s_sm[231]), s_sm[232]);
        float invs = rsqrtf(vs);
        #pragma unroll
        for (int i = 0; i < 4; ++i) {
            float r = fmaf(ex, As[i], Ds[i]);
            r = fmaf(r, invs, sl[i]);
            s_X[tok * 65 + jb + i]      = fmaxf(r, 0.f);
            s_X[tok * 65 + 32 + jb + i] = nsum[i];
        }
    }
    __syncthreads();

    // ---- phase B1: u = X @ W2 (+bias). wave w owns u-channels [8w, 8w+8) ----
    //      w<4: self half via sW2 over X[0..32); w>=4: neighbor half via nW2 over X[32..64).
    //      Weights are wave-uniform -> s_load; index identity: 8w+i covers both halves.
    const int w = __builtin_amdgcn_readfirstlane(t >> 6);
    const int l = t & 63;
    {
        const float* W2  = (w < 4) ? sW2 : nW2;
        const int   i0   = (w & 3) * 8;
        const int   xoff = (w < 4) ? 0 : 32;
        float u[8];
        #pragma unroll
        for (int i = 0; i < 8; ++i)
            u[i] = (w < 4) ? sb2[i0 + i] : 32.f * nb2[i0 + i];
        #pragma unroll 4
        for (int k = 0; k < 32; ++k) {
            float xk = s_X[l * 65 + xoff + k];             // 2-way bank alias: free
            const float* wr = W2 + k * 32 + i0;            // uniform -> s_load
            #pragma unroll
            for (int i = 0; i < 8; ++i) u[i] = fmaf(xk, wr[i], u[i]);
        }
        #pragma unroll
        for (int i = 0; i < 8; ++i) s_U[l * 65 + 8 * w + i] = u[i];
    }
    __syncthreads();

    // ---- phase B2: y = u @ hW1 + hb1. wave w owns y-channels [8w, 8w+8) ----
    float y[8];
    #pragma unroll
    for (int i = 0; i < 8; ++i) y[i] = hb1[8 * w + i];
    #pragma unroll 4
    for (int k = 0; k < 64; ++k) {
        float uk = s_U[l * 65 + k];
        const float* hr = hW1 + k * 64 + 8 * w;            // uniform -> s_load
        #pragma unroll
        for (int i = 0; i < 8; ++i) y[i] = fmaf(uk, hr[i], y[i]);
    }

    // ---- LN over 64 channels (split across 8 waves) ----
    float sm = 0.f, s2 = 0.f;
    #pragma unroll
    for (int i = 0; i < 8; ++i) { sm += y[i]; s2 = fmaf(y[i], y[i], s2); }
    s_red[l * 17 + w * 2 + 0] = sm;
    s_red[l * 17 + w * 2 + 1] = s2;
    __syncthreads();
    float tot = 0.f, tot2 = 0.f;
    #pragma unroll
    for (int r = 0; r < 8; ++r) {
        tot  += s_red[l * 17 + r * 2 + 0];
        tot2 += s_red[l * 17 + r * 2 + 1];
    }
    float mean = tot * (1.f / 64.f);
    float var  = tot2 * (1.f / 64.f) - mean * mean;
    float linv = rsqrtf(var + LN_EPS);
    #pragma unroll
    for (int i = 0; i < 8; ++i) {
        float v = (y[i] - mean) * linv;
        v = fmaf(v, hlg[w * 8 + i], hlb[w * 8 + i]);
        s_X[l * 65 + w * 8 + i] = fmaxf(v, 0.f);           // reuse s_X for Y'
    }
    __syncthreads();

    // ---- phase C: out = Y' @ hW2 + hb2. wave w owns out channels [4w, 4w+4) ----
    const int ob = w * 4;
    int mk = mask[g0 + l];                                 // early load
    float o[4];
    #pragma unroll
    for (int i = 0; i < 4; ++i) o[i] = hb2[ob + i];
    #pragma unroll 4
    for (int m = 0; m < 64; ++m) {
        float ym = s_X[l * 65 + m];
        const float* h2 = hW2 + m * 32 + ob;               // uniform -> s_load
        #pragma unroll
        for (int i = 0; i < 4; ++i) o[i] = fmaf(ym, h2[i], o[i]);
    }
    float4 ov = make_float4(o[0], o[1], o[2], o[3]);
    if (mk) ov = make_float4(0.f, 0.f, 0.f, 0.f);
    *(float4*)(out + (size_t)(g0 + l) * 32 + ob) = ov;
}

extern "C" void kernel_launch(void* const* d_in, const int* in_sizes, int n_in,
                              void* d_out, int out_size, void* d_ws, size_t ws_size,
                              hipStream_t stream) {
    const float* expr      = (const float*)d_in[0];
    const float* neighbors = (const float*)d_in[1];
    const float* edge_info = (const float*)d_in[2];
    const int*   mask      = (const int*)d_in[3];
    const float* nW1 = (const float*)d_in[4];
    const float* nb1 = (const float*)d_in[5];
    const float* nlg = (const float*)d_in[6];
    const float* nlb = (const float*)d_in[7];
    const float* nW2 = (const float*)d_in[8];
    const float* nb2 = (const float*)d_in[9];
    const float* sW1 = (const float*)d_in[10];
    const float* sb1 = (const float*)d_in[11];
    const float* slg = (const float*)d_in[12];
    const float* slb = (const float*)d_in[13];
    const float* sW2 = (const float*)d_in[14];
    const float* sb2 = (const float*)d_in[15];
    const float* hW1 = (const float*)d_in[16];
    const float* hb1 = (const float*)d_in[17];
    const float* hlg = (const float*)d_in[18];
    const float* hlb = (const float*)d_in[19];
    const float* hW2 = (const float*)d_in[20];
    const float* hb2 = (const float*)d_in[21];
    float* out = (float*)d_out;

    gnn_all<<<512, 512, 0, stream>>>(expr, neighbors, edge_info, mask,
                                     nW1, nb1, nlg, nlb, nW2, nb2,
                                     sW1, sb1, slg, slb, sW2, sb2,
                                     hW1, hb1, hlg, hlb, hW2, hb2, out);
}